// Round 1
// baseline (567.759 us; speedup 1.0000x reference)
//
#include <hip/hip_runtime.h>

// LNSNet forward: conv1(1->32,3x3)+ReLU+pool2 -> conv2(32->64,3x3)+ReLU+pool2
//                 -> fc1(9216->128)+ReLU -> fc2(128->10)
// B=512. All fp32. Round 0: correct fp32 baseline, no MFMA yet.

#define B 512
#define H1 54
#define P1H 26       // pooled conv1 output 26x26, 32 ch
#define P1SZ (32*26*26)
#define P2SZ (64*12*12)

// ---------------- conv1 + relu + maxpool2 ----------------
// one thread per pooled output element [b,c,py,px] -> 512*32*26*26 threads
__global__ void conv1_pool(const float* __restrict__ x, const float* __restrict__ w,
                           const float* __restrict__ bias, float* __restrict__ out) {
    int t = blockIdx.x * blockDim.x + threadIdx.x;
    const int total = B * 32 * 26 * 26;
    if (t >= total) return;
    int px = t % 26;
    int py = (t / 26) % 26;
    int c  = (t / (26 * 26)) % 32;
    int b  = t / (26 * 26 * 32);

    const float* wp = w + c * 9;
    float w00 = wp[0], w01 = wp[1], w02 = wp[2];
    float w10 = wp[3], w11 = wp[4], w12 = wp[5];
    float w20 = wp[6], w21 = wp[7], w22 = wp[8];

    const float* xin = x + b * (54 * 54) + (2 * py) * 54 + 2 * px;
    float in[4][4];
#pragma unroll
    for (int r = 0; r < 4; ++r) {
        float2 a  = *reinterpret_cast<const float2*>(xin + r * 54);
        float2 c2 = *reinterpret_cast<const float2*>(xin + r * 54 + 2);
        in[r][0] = a.x; in[r][1] = a.y; in[r][2] = c2.x; in[r][3] = c2.y;
    }
    float m = -1e30f;
#pragma unroll
    for (int dy = 0; dy < 2; ++dy)
#pragma unroll
        for (int dx = 0; dx < 2; ++dx) {
            float s = in[dy + 0][dx + 0] * w00 + in[dy + 0][dx + 1] * w01 + in[dy + 0][dx + 2] * w02
                    + in[dy + 1][dx + 0] * w10 + in[dy + 1][dx + 1] * w11 + in[dy + 1][dx + 2] * w12
                    + in[dy + 2][dx + 0] * w20 + in[dy + 2][dx + 1] * w21 + in[dy + 2][dx + 2] * w22;
            m = fmaxf(m, s);
        }
    out[t] = fmaxf(m + bias[c], 0.0f);
}

// ---------------- conv2 + relu + maxpool2 ----------------
// one thread per pooled output element [b,oc,py,px] -> 512*64*12*12 threads
__global__ void conv2_pool(const float* __restrict__ p1, const float* __restrict__ w,
                           const float* __restrict__ bias, float* __restrict__ out) {
    int t = blockIdx.x * blockDim.x + threadIdx.x;
    const int total = B * 64 * 12 * 12;
    if (t >= total) return;
    int px = t % 12;
    int py = (t / 12) % 12;
    int oc = (t / 144) % 64;
    int b  = t / (144 * 64);

    const float* inb = p1 + b * (32 * 26 * 26) + (2 * py) * 26 + 2 * px;
    const float* wb  = w + oc * (32 * 9);

    float s00 = 0.f, s01 = 0.f, s10 = 0.f, s11 = 0.f;
    for (int ic = 0; ic < 32; ++ic) {
        const float* xin = inb + ic * 676;
        float in[4][4];
#pragma unroll
        for (int r = 0; r < 4; ++r) {
            float2 a  = *reinterpret_cast<const float2*>(xin + r * 26);
            float2 c2 = *reinterpret_cast<const float2*>(xin + r * 26 + 2);
            in[r][0] = a.x; in[r][1] = a.y; in[r][2] = c2.x; in[r][3] = c2.y;
        }
        const float* wp = wb + ic * 9;
        float w00 = wp[0], w01 = wp[1], w02 = wp[2];
        float w10 = wp[3], w11 = wp[4], w12 = wp[5];
        float w20 = wp[6], w21 = wp[7], w22 = wp[8];
#pragma unroll
        for (int dy = 0; dy < 2; ++dy) {
#pragma unroll
            for (int dx = 0; dx < 2; ++dx) {
                float s = in[dy + 0][dx + 0] * w00 + in[dy + 0][dx + 1] * w01 + in[dy + 0][dx + 2] * w02
                        + in[dy + 1][dx + 0] * w10 + in[dy + 1][dx + 1] * w11 + in[dy + 1][dx + 2] * w12
                        + in[dy + 2][dx + 0] * w20 + in[dy + 2][dx + 1] * w21 + in[dy + 2][dx + 2] * w22;
                if (dy == 0 && dx == 0) s00 += s;
                else if (dy == 0) s01 += s;
                else if (dx == 0) s10 += s;
                else s11 += s;
            }
        }
    }
    float m = fmaxf(fmaxf(s00, s01), fmaxf(s10, s11));
    out[t] = fmaxf(m + bias[oc], 0.0f);
}

// ---------------- fc1 + relu ----------------
// wave computes a 4(batch) x 4(out) tile; lanes split K=9216, shuffle reduce.
// waves = 128 bgroups * 32 ogroups = 4096; block=256 -> 1024 blocks
__global__ void fc1_relu(const float* __restrict__ h, const float* __restrict__ w,
                         const float* __restrict__ bias, float* __restrict__ out) {
    int gid  = blockIdx.x * blockDim.x + threadIdx.x;
    int wid  = gid >> 6;
    int lane = threadIdx.x & 63;
    int og = wid & 31;   // 32 groups of 4 outputs
    int bg = wid >> 5;   // 128 groups of 4 batches
    int o0 = og * 4, b0 = bg * 4;

    float acc[4][4] = {{0.f}};
#pragma unroll 2
    for (int k = lane; k < 9216; k += 64) {
        float hv[4], wv[4];
#pragma unroll
        for (int i = 0; i < 4; ++i) hv[i] = h[(b0 + i) * 9216 + k];
#pragma unroll
        for (int j = 0; j < 4; ++j) wv[j] = w[(o0 + j) * 9216 + k];
#pragma unroll
        for (int i = 0; i < 4; ++i)
#pragma unroll
            for (int j = 0; j < 4; ++j) acc[i][j] += hv[i] * wv[j];
    }
#pragma unroll
    for (int i = 0; i < 4; ++i)
#pragma unroll
        for (int j = 0; j < 4; ++j) {
            float v = acc[i][j];
#pragma unroll
            for (int s = 32; s > 0; s >>= 1) v += __shfl_down(v, s, 64);
            if (lane == 0)
                out[(b0 + i) * 128 + (o0 + j)] = fmaxf(v + bias[o0 + j], 0.0f);
        }
}

// ---------------- fc2 ----------------
__global__ void fc2_k(const float* __restrict__ h, const float* __restrict__ w,
                      const float* __restrict__ bias, float* __restrict__ out) {
    int t = blockIdx.x * blockDim.x + threadIdx.x;
    if (t >= B * 10) return;
    int o = t % 10, b = t / 10;
    const float* hp = h + b * 128;
    const float* wp = w + o * 128;
    float s = 0.f;
#pragma unroll 8
    for (int k = 0; k < 128; ++k) s += hp[k] * wp[k];
    out[t] = s + bias[o];
}

extern "C" void kernel_launch(void* const* d_in, const int* in_sizes, int n_in,
                              void* d_out, int out_size, void* d_ws, size_t ws_size,
                              hipStream_t stream) {
    const float* x       = (const float*)d_in[0];
    const float* conv1_w = (const float*)d_in[1];
    const float* conv1_b = (const float*)d_in[2];
    const float* conv2_w = (const float*)d_in[3];
    const float* conv2_b = (const float*)d_in[4];
    const float* fc1_w   = (const float*)d_in[5];
    const float* fc1_b   = (const float*)d_in[6];
    const float* fc2_w   = (const float*)d_in[7];
    const float* fc2_b   = (const float*)d_in[8];
    float* out = (float*)d_out;

    float* ws = (float*)d_ws;
    float* pool1 = ws;                                  // 512*32*26*26 = 11,075,584 floats
    float* pool2 = pool1 + (size_t)B * P1SZ;            // 512*64*12*12 =  4,718,592 floats
    float* h3    = pool2 + (size_t)B * P2SZ;            // 512*128      =     65,536 floats

    {   // conv1 + pool: 11,075,584 threads
        int total = B * 32 * 26 * 26;
        conv1_pool<<<(total + 255) / 256, 256, 0, stream>>>(x, conv1_w, conv1_b, pool1);
    }
    {   // conv2 + pool: 4,718,592 threads
        int total = B * 64 * 12 * 12;
        conv2_pool<<<(total + 255) / 256, 256, 0, stream>>>(pool1, conv2_w, conv2_b, pool2);
    }
    {   // fc1: 4096 waves = 1024 blocks of 256
        fc1_relu<<<1024, 256, 0, stream>>>(pool2, fc1_w, fc1_b, h3);
    }
    {   // fc2: 5120 outputs
        fc2_k<<<20, 256, 0, stream>>>(h3, fc2_w, fc2_b, out);
    }
}

// Round 2
// 196.968 us; speedup vs baseline: 2.8825x; 2.8825x over previous
//
#include <hip/hip_runtime.h>

// LNSNet forward, R1: conv2 as bf16 MFMA implicit GEMM (one image per block).
// conv1 emits pool1 channels-last bf16 [b][pos=26x26][ic=32]; conv2 stages it
// into LDS (ic padded 32->40 for bank-friendly strides), computes M=576,N=64,
// K=288 with mfma_f32_16x16x32_bf16, pools in regs+LDS scratch, writes pool2
// NCHW fp32 so fc1/fc2 are unchanged from R0.

#define B 512
#define POS 676            // 26*26 pooled conv1 spatial
#define ICP 40             // padded ic stride in LDS (stride 80B = 20 dwords, conflict-free)
#define P2SZ (64*12*12)

typedef unsigned short ushort_t;
typedef ushort_t ushort4v __attribute__((ext_vector_type(4)));
typedef short s16x8 __attribute__((ext_vector_type(8)));
typedef float f32x4 __attribute__((ext_vector_type(4)));

__device__ __forceinline__ ushort_t f2bf(float f) {
    union { float f; unsigned u; } a; a.f = f;
    unsigned r = a.u + 0x7FFFu + ((a.u >> 16) & 1u);   // RNE
    return (ushort_t)(r >> 16);
}
__device__ __forceinline__ float bf2f(ushort_t u) {
    union { unsigned u; float f; } a; a.u = ((unsigned)u) << 16;
    return a.f;
}

// ---------------- conv1 + relu + maxpool2, channels-last bf16 out ----------------
// one thread per output element [b][pos][ic]; adjacent lanes = adjacent ic
// -> patch loads are wave-broadcast, weight rows L1-resident, stores coalesced.
__global__ void conv1_pool_cl(const float* __restrict__ x, const float* __restrict__ w,
                              const float* __restrict__ bias, ushort_t* __restrict__ out) {
    int t = blockIdx.x * blockDim.x + threadIdx.x;
    const int total = B * POS * 32;
    if (t >= total) return;
    int ic  = t & 31;
    int r   = t >> 5;
    int pos = r % POS;
    int b   = r / POS;
    int py = pos / 26, px = pos % 26;

    const float* wp = w + ic * 9;
    float w00 = wp[0], w01 = wp[1], w02 = wp[2];
    float w10 = wp[3], w11 = wp[4], w12 = wp[5];
    float w20 = wp[6], w21 = wp[7], w22 = wp[8];

    const float* xin = x + b * (54 * 54) + (2 * py) * 54 + 2 * px;
    float in[4][4];
#pragma unroll
    for (int rr = 0; rr < 4; ++rr) {
        float2 a  = *reinterpret_cast<const float2*>(xin + rr * 54);
        float2 c2 = *reinterpret_cast<const float2*>(xin + rr * 54 + 2);
        in[rr][0] = a.x; in[rr][1] = a.y; in[rr][2] = c2.x; in[rr][3] = c2.y;
    }
    float m = -1e30f;
#pragma unroll
    for (int dy = 0; dy < 2; ++dy)
#pragma unroll
        for (int dx = 0; dx < 2; ++dx) {
            float s = in[dy + 0][dx + 0] * w00 + in[dy + 0][dx + 1] * w01 + in[dy + 0][dx + 2] * w02
                    + in[dy + 1][dx + 0] * w10 + in[dy + 1][dx + 1] * w11 + in[dy + 1][dx + 2] * w12
                    + in[dy + 2][dx + 0] * w20 + in[dy + 2][dx + 1] * w21 + in[dy + 2][dx + 2] * w22;
            m = fmaxf(m, s);
        }
    out[t] = f2bf(fmaxf(m + bias[ic], 0.0f));
}

// ---------------- conv2 weight reshuffle: [oc][ic][3][3] f32 -> [oc][tap][ic] bf16 ----------------
__global__ void conv2_wprep(const float* __restrict__ w, ushort_t* __restrict__ wr) {
    int t = blockIdx.x * blockDim.x + threadIdx.x;
    if (t >= 64 * 9 * 32) return;
    int ic  = t & 31;
    int tap = (t >> 5) % 9;
    int oc  = t / 288;
    wr[t] = f2bf(w[oc * 288 + ic * 9 + tap]);
}

// ---------------- conv2 MFMA implicit GEMM + relu + pool ----------------
// block = 768 threads (12 waves), one image. Wave w handles conv rows 2w,2w+1
// (48 positions = 3 M-tiles) x 64 oc (4 N-tiles), K = 9 taps x 32 ic.
__global__ __launch_bounds__(768) void conv2_mfma(const ushort_t* __restrict__ p1,
                                                  const ushort_t* __restrict__ wr,
                                                  const float* __restrict__ bias,
                                                  float* __restrict__ pool2) {
    __shared__ ushort_t lds[POS * ICP];   // 27040 ushort = 54,080 B
    int b   = blockIdx.x;
    int tid = threadIdx.x;

    // ---- stage image: global [pos][32] -> LDS [pos][40] ----
    const ushort_t* src = p1 + (size_t)b * POS * 32;
    for (int c = tid; c < POS * 8; c += 768) {
        int pos = c >> 3, off = (c & 7) * 4;
        ushort4v v = *reinterpret_cast<const ushort4v*>(src + pos * 32 + off);
        *reinterpret_cast<ushort4v*>(&lds[pos * ICP + off]) = v;
    }
    __syncthreads();

    int lane = tid & 63, wid = tid >> 6;
    int quad = lane >> 4, lr = lane & 15;

    // per-tile A-row base element index (sans tap offset)
    int ebase[3];
#pragma unroll
    for (int t = 0; t < 3; ++t) {
        int m  = t * 16 + lr;            // 0..47 within wave
        int yl = m / 24;                 // 0 or 1
        int xx = m - yl * 24;            // 0..23
        ebase[t] = ((wid * 2 + yl) * 26 + xx) * ICP + quad * 8;
    }

    f32x4 acc[3][4];
#pragma unroll
    for (int t = 0; t < 3; ++t)
#pragma unroll
        for (int n = 0; n < 4; ++n) acc[t][n] = (f32x4){0.f, 0.f, 0.f, 0.f};

    // B-frag base: oc = nt*16+lr ; elem = oc*288 + tap*32 + quad*8
    const ushort_t* wb = wr + (size_t)lr * 288 + quad * 8;

#pragma unroll
    for (int tap = 0; tap < 9; ++tap) {
        int ky = tap / 3, kx = tap % 3;
        int koff = (ky * 26 + kx) * ICP;
        s16x8 a[3];
#pragma unroll
        for (int t = 0; t < 3; ++t) {
            union { ushort4v s[2]; s16x8 v; } u;
            u.s[0] = *reinterpret_cast<const ushort4v*>(&lds[ebase[t] + koff]);
            u.s[1] = *reinterpret_cast<const ushort4v*>(&lds[ebase[t] + koff + 4]);
            a[t] = u.v;
        }
        s16x8 bf[4];
#pragma unroll
        for (int n = 0; n < 4; ++n)
            bf[n] = *reinterpret_cast<const s16x8*>(wb + n * 4608 + tap * 32);
#pragma unroll
        for (int t = 0; t < 3; ++t)
#pragma unroll
            for (int n = 0; n < 4; ++n)
                acc[t][n] = __builtin_amdgcn_mfma_f32_16x16x32_bf16(a[t], bf[n], acc[t][n], 0, 0, 0);
    }
    __syncthreads();   // image LDS now dead; reuse as pooling scratch

    // ---- x-pool in registers, write scratch [wid][oc][i], i=m'/2 (0..23) ----
    // C layout: col(oc within tile)=lane&15, row(m within tile)=quad*4+reg
    ushort_t* scr = lds + wid * 1536;    // 64 oc * 24
#pragma unroll
    for (int t = 0; t < 3; ++t)
#pragma unroll
        for (int n = 0; n < 4; ++n) {
            int oc = n * 16 + lr;
            int i0 = t * 8 + quad * 2;
            float v0 = fmaxf(acc[t][n][0], acc[t][n][1]);
            float v1 = fmaxf(acc[t][n][2], acc[t][n][3]);
            union { ushort_t u2[2]; unsigned w; } p;
            p.u2[0] = f2bf(v0); p.u2[1] = f2bf(v1);
            *reinterpret_cast<unsigned*>(&scr[oc * 24 + i0]) = p.w;
        }
    __syncthreads();

    // ---- y-pool: lane=oc, pooled row py=wid; scratch i<12 is row0, i>=12 row1 ----
    int oc = lane;
    const ushort_t* row = scr + oc * 24;
    float bv = bias[oc];
    float outv[12];
#pragma unroll
    for (int px = 0; px < 12; ++px) {
        float r0 = bf2f(row[px]);
        float r1 = bf2f(row[px + 12]);
        outv[px] = fmaxf(fmaxf(r0, r1) + bv, 0.0f);
    }
    float4* po = reinterpret_cast<float4*>(pool2 + ((size_t)(b * 64 + oc) * 144 + wid * 12));
    po[0] = make_float4(outv[0], outv[1], outv[2], outv[3]);
    po[1] = make_float4(outv[4], outv[5], outv[6], outv[7]);
    po[2] = make_float4(outv[8], outv[9], outv[10], outv[11]);
}

// ---------------- fc1 + relu (unchanged from R0) ----------------
__global__ void fc1_relu(const float* __restrict__ h, const float* __restrict__ w,
                         const float* __restrict__ bias, float* __restrict__ out) {
    int gid  = blockIdx.x * blockDim.x + threadIdx.x;
    int wid  = gid >> 6;
    int lane = threadIdx.x & 63;
    int og = wid & 31;
    int bg = wid >> 5;
    int o0 = og * 4, b0 = bg * 4;

    float acc[4][4] = {{0.f}};
#pragma unroll 2
    for (int k = lane; k < 9216; k += 64) {
        float hv[4], wv[4];
#pragma unroll
        for (int i = 0; i < 4; ++i) hv[i] = h[(b0 + i) * 9216 + k];
#pragma unroll
        for (int j = 0; j < 4; ++j) wv[j] = w[(o0 + j) * 9216 + k];
#pragma unroll
        for (int i = 0; i < 4; ++i)
#pragma unroll
            for (int j = 0; j < 4; ++j) acc[i][j] += hv[i] * wv[j];
    }
#pragma unroll
    for (int i = 0; i < 4; ++i)
#pragma unroll
        for (int j = 0; j < 4; ++j) {
            float v = acc[i][j];
#pragma unroll
            for (int s = 32; s > 0; s >>= 1) v += __shfl_down(v, s, 64);
            if (lane == 0)
                out[(b0 + i) * 128 + (o0 + j)] = fmaxf(v + bias[o0 + j], 0.0f);
        }
}

// ---------------- fc2 (unchanged) ----------------
__global__ void fc2_k(const float* __restrict__ h, const float* __restrict__ w,
                      const float* __restrict__ bias, float* __restrict__ out) {
    int t = blockIdx.x * blockDim.x + threadIdx.x;
    if (t >= B * 10) return;
    int o = t % 10, b = t / 10;
    const float* hp = h + b * 128;
    const float* wp = w + o * 128;
    float s = 0.f;
#pragma unroll 8
    for (int k = 0; k < 128; ++k) s += hp[k] * wp[k];
    out[t] = s + bias[o];
}

extern "C" void kernel_launch(void* const* d_in, const int* in_sizes, int n_in,
                              void* d_out, int out_size, void* d_ws, size_t ws_size,
                              hipStream_t stream) {
    const float* x       = (const float*)d_in[0];
    const float* conv1_w = (const float*)d_in[1];
    const float* conv1_b = (const float*)d_in[2];
    const float* conv2_w = (const float*)d_in[3];
    const float* conv2_b = (const float*)d_in[4];
    const float* fc1_w   = (const float*)d_in[5];
    const float* fc1_b   = (const float*)d_in[6];
    const float* fc2_w   = (const float*)d_in[7];
    const float* fc2_b   = (const float*)d_in[8];
    float* out = (float*)d_out;

    // workspace layout
    char* ws = (char*)d_ws;
    ushort_t* pool1 = (ushort_t*)ws;                         // 512*676*32 bf16 = 22.1 MB
    ws += (size_t)B * POS * 32 * sizeof(ushort_t);
    ushort_t* wr = (ushort_t*)ws;                            // 64*9*32 bf16 = 36,864 B
    ws += 64 * 9 * 32 * sizeof(ushort_t) + 128;              // pad
    float* pool2 = (float*)ws;                               // 512*64*144 f32 = 18.9 MB
    ws += (size_t)B * P2SZ * sizeof(float);
    float* h3 = (float*)ws;                                  // 512*128 f32

    {   // conv1 + pool, channels-last bf16: 11,075,584 threads
        int total = B * POS * 32;
        conv1_pool_cl<<<(total + 255) / 256, 256, 0, stream>>>(x, conv1_w, conv1_b, pool1);
    }
    {   // conv2 weight reshuffle: 18,432 elems
        conv2_wprep<<<72, 256, 0, stream>>>(conv2_w, wr);
    }
    {   // conv2 MFMA: one block per image
        conv2_mfma<<<B, 768, 0, stream>>>(pool1, wr, conv2_b, pool2);
    }
    {   // fc1
        fc1_relu<<<1024, 256, 0, stream>>>(pool2, fc1_w, fc1_b, h3);
    }
    {   // fc2
        fc2_k<<<20, 256, 0, stream>>>(h3, fc2_w, fc2_b, out);
    }
}

// Round 3
// 167.513 us; speedup vs baseline: 3.3893x; 1.1758x over previous
//
#include <hip/hip_runtime.h>

// LNSNet forward, R2: conv2 (bf16 MFMA implicit GEMM) now emits pool2 bf16;
// fc1 becomes a bf16 MFMA split-K GEMM (M=512,N=128,K=9216) with fp32 atomic
// accumulation; fc2 fuses fc1's bias+ReLU epilogue.

#define B 512
#define POS 676            // 26*26 pooled conv1 spatial
#define ICP 40             // padded ic stride in LDS
#define P2SZ (64*12*12)    // 9216

typedef unsigned short ushort_t;
typedef ushort_t ushort4v __attribute__((ext_vector_type(4)));
typedef short s16x8 __attribute__((ext_vector_type(8)));
typedef float f32x4 __attribute__((ext_vector_type(4)));

__device__ __forceinline__ ushort_t f2bf(float f) {
    union { float f; unsigned u; } a; a.f = f;
    unsigned r = a.u + 0x7FFFu + ((a.u >> 16) & 1u);   // RNE
    return (ushort_t)(r >> 16);
}
__device__ __forceinline__ float bf2f(ushort_t u) {
    union { unsigned u; float f; } a; a.u = ((unsigned)u) << 16;
    return a.f;
}

// ---------------- conv1 + relu + maxpool2, channels-last bf16 out ----------------
__global__ void conv1_pool_cl(const float* __restrict__ x, const float* __restrict__ w,
                              const float* __restrict__ bias, ushort_t* __restrict__ out) {
    int t = blockIdx.x * blockDim.x + threadIdx.x;
    const int total = B * POS * 32;
    if (t >= total) return;
    int ic  = t & 31;
    int r   = t >> 5;
    int pos = r % POS;
    int b   = r / POS;
    int py = pos / 26, px = pos % 26;

    const float* wp = w + ic * 9;
    float w00 = wp[0], w01 = wp[1], w02 = wp[2];
    float w10 = wp[3], w11 = wp[4], w12 = wp[5];
    float w20 = wp[6], w21 = wp[7], w22 = wp[8];

    const float* xin = x + b * (54 * 54) + (2 * py) * 54 + 2 * px;
    float in[4][4];
#pragma unroll
    for (int rr = 0; rr < 4; ++rr) {
        float2 a  = *reinterpret_cast<const float2*>(xin + rr * 54);
        float2 c2 = *reinterpret_cast<const float2*>(xin + rr * 54 + 2);
        in[rr][0] = a.x; in[rr][1] = a.y; in[rr][2] = c2.x; in[rr][3] = c2.y;
    }
    float m = -1e30f;
#pragma unroll
    for (int dy = 0; dy < 2; ++dy)
#pragma unroll
        for (int dx = 0; dx < 2; ++dx) {
            float s = in[dy + 0][dx + 0] * w00 + in[dy + 0][dx + 1] * w01 + in[dy + 0][dx + 2] * w02
                    + in[dy + 1][dx + 0] * w10 + in[dy + 1][dx + 1] * w11 + in[dy + 1][dx + 2] * w12
                    + in[dy + 2][dx + 0] * w20 + in[dy + 2][dx + 1] * w21 + in[dy + 2][dx + 2] * w22;
            m = fmaxf(m, s);
        }
    out[t] = f2bf(fmaxf(m + bias[ic], 0.0f));
}

// ---------------- prep: conv2 w reshuffle + fc1 w bf16 + zero fc1 accumulator ----------------
#define N_WR   (64 * 9 * 32)        // 18432
#define N_WF   (128 * 9216)         // 1179648
#define N_ZERO (512 * 128)          // 65536
__global__ void prep_k(const float* __restrict__ c2w, const float* __restrict__ f1w,
                       ushort_t* __restrict__ wr, ushort_t* __restrict__ wfb,
                       float* __restrict__ h3raw) {
    int t = blockIdx.x * blockDim.x + threadIdx.x;
    if (t < N_WR) {
        int ic  = t & 31;
        int tap = (t >> 5) % 9;
        int oc  = t / 288;
        wr[t] = f2bf(c2w[oc * 288 + ic * 9 + tap]);
    } else if (t < N_WR + N_WF) {
        int i = t - N_WR;
        wfb[i] = f2bf(f1w[i]);
    } else if (t < N_WR + N_WF + N_ZERO) {
        h3raw[t - N_WR - N_WF] = 0.0f;
    }
}

// ---------------- conv2 MFMA implicit GEMM + relu + pool -> bf16 NCHW ----------------
__global__ __launch_bounds__(768) void conv2_mfma(const ushort_t* __restrict__ p1,
                                                  const ushort_t* __restrict__ wr,
                                                  const float* __restrict__ bias,
                                                  ushort_t* __restrict__ pool2) {
    __shared__ ushort_t lds[POS * ICP];   // 54,080 B
    int b   = blockIdx.x;
    int tid = threadIdx.x;

    const ushort_t* src = p1 + (size_t)b * POS * 32;
    for (int c = tid; c < POS * 8; c += 768) {
        int pos = c >> 3, off = (c & 7) * 4;
        ushort4v v = *reinterpret_cast<const ushort4v*>(src + pos * 32 + off);
        *reinterpret_cast<ushort4v*>(&lds[pos * ICP + off]) = v;
    }
    __syncthreads();

    int lane = tid & 63, wid = tid >> 6;
    int quad = lane >> 4, lr = lane & 15;

    int ebase[3];
#pragma unroll
    for (int t = 0; t < 3; ++t) {
        int m  = t * 16 + lr;
        int yl = m / 24;
        int xx = m - yl * 24;
        ebase[t] = ((wid * 2 + yl) * 26 + xx) * ICP + quad * 8;
    }

    f32x4 acc[3][4];
#pragma unroll
    for (int t = 0; t < 3; ++t)
#pragma unroll
        for (int n = 0; n < 4; ++n) acc[t][n] = (f32x4){0.f, 0.f, 0.f, 0.f};

    const ushort_t* wb = wr + (size_t)lr * 288 + quad * 8;

#pragma unroll
    for (int tap = 0; tap < 9; ++tap) {
        int ky = tap / 3, kx = tap % 3;
        int koff = (ky * 26 + kx) * ICP;
        s16x8 a[3];
#pragma unroll
        for (int t = 0; t < 3; ++t) {
            union { ushort4v s[2]; s16x8 v; } u;
            u.s[0] = *reinterpret_cast<const ushort4v*>(&lds[ebase[t] + koff]);
            u.s[1] = *reinterpret_cast<const ushort4v*>(&lds[ebase[t] + koff + 4]);
            a[t] = u.v;
        }
        s16x8 bf[4];
#pragma unroll
        for (int n = 0; n < 4; ++n)
            bf[n] = *reinterpret_cast<const s16x8*>(wb + n * 4608 + tap * 32);
#pragma unroll
        for (int t = 0; t < 3; ++t)
#pragma unroll
            for (int n = 0; n < 4; ++n)
                acc[t][n] = __builtin_amdgcn_mfma_f32_16x16x32_bf16(a[t], bf[n], acc[t][n], 0, 0, 0);
    }
    __syncthreads();

    // x-pool in regs -> LDS scratch [wid][oc][i]
    ushort_t* scr = lds + wid * 1536;
#pragma unroll
    for (int t = 0; t < 3; ++t)
#pragma unroll
        for (int n = 0; n < 4; ++n) {
            int oc = n * 16 + lr;
            int i0 = t * 8 + quad * 2;
            float v0 = fmaxf(acc[t][n][0], acc[t][n][1]);
            float v1 = fmaxf(acc[t][n][2], acc[t][n][3]);
            union { ushort_t u2[2]; unsigned w; } p;
            p.u2[0] = f2bf(v0); p.u2[1] = f2bf(v1);
            *reinterpret_cast<unsigned*>(&scr[oc * 24 + i0]) = p.w;
        }
    __syncthreads();

    // y-pool: lane=oc, pooled row = wid; emit bf16 NCHW (k = oc*144 + wid*12 + px)
    int oc = lane;
    const ushort_t* row = scr + oc * 24;
    float bv = bias[oc];
    ushort_t outv[12];
#pragma unroll
    for (int px = 0; px < 12; ++px) {
        float r0 = bf2f(row[px]);
        float r1 = bf2f(row[px + 12]);
        outv[px] = f2bf(fmaxf(fmaxf(r0, r1) + bv, 0.0f));
    }
    ushort_t* po = pool2 + ((size_t)(b * 64 + oc) * 144 + wid * 12);
#pragma unroll
    for (int q = 0; q < 3; ++q)
        *reinterpret_cast<ushort4v*>(po + q * 4) =
            (ushort4v){outv[q*4+0], outv[q*4+1], outv[q*4+2], outv[q*4+3]};
}

// ---------------- fc1 as bf16 MFMA split-K GEMM ----------------
// grid = 8 M-tiles x 32 K-splits = 256 blocks, 256 thr (4 waves).
// wave: 16(M) x 128(N) via 8 n-tiles, K-chunk 288 (9 ksteps); atomicAdd fp32.
__global__ __launch_bounds__(256) void fc1_mfma(const ushort_t* __restrict__ A,
                                                 const ushort_t* __restrict__ W,
                                                 float* __restrict__ Craw) {
    int blk = blockIdx.x;
    int mt = blk & 7;
    int ks = blk >> 3;
    int tid = threadIdx.x;
    int lane = tid & 63, wid = tid >> 6;
    int lr = lane & 15, quad = lane >> 4;

    int m  = mt * 64 + wid * 16 + lr;
    int k0 = ks * 288;
    const ushort_t* arow = A + (size_t)m * 9216 + k0 + quad * 8;
    const ushort_t* wrow = W + (size_t)lr * 9216 + k0 + quad * 8;

    f32x4 acc[8];
#pragma unroll
    for (int n = 0; n < 8; ++n) acc[n] = (f32x4){0.f, 0.f, 0.f, 0.f};

#pragma unroll
    for (int kk = 0; kk < 9; ++kk) {
        s16x8 a = *reinterpret_cast<const s16x8*>(arow + kk * 32);
#pragma unroll
        for (int n = 0; n < 8; ++n) {
            s16x8 bfr = *reinterpret_cast<const s16x8*>(wrow + (size_t)n * 16 * 9216 + kk * 32);
            acc[n] = __builtin_amdgcn_mfma_f32_16x16x32_bf16(a, bfr, acc[n], 0, 0, 0);
        }
    }

    // C layout: col = lr (n within tile), row = quad*4 + reg
    int crow = mt * 64 + wid * 16 + quad * 4;
#pragma unroll
    for (int n = 0; n < 8; ++n)
#pragma unroll
        for (int r = 0; r < 4; ++r)
            atomicAdd(&Craw[(size_t)(crow + r) * 128 + n * 16 + lr], acc[n][r]);
}

// ---------------- fc2 with fused fc1 bias+ReLU ----------------
__global__ void fc2_fused(const float* __restrict__ h3raw, const float* __restrict__ b1,
                          const float* __restrict__ w, const float* __restrict__ b2,
                          float* __restrict__ out) {
    int t = blockIdx.x * blockDim.x + threadIdx.x;
    if (t >= B * 10) return;
    int o = t % 10, bb = t / 10;
    const float* hp = h3raw + bb * 128;
    const float* wp = w + o * 128;
    float s = 0.f;
#pragma unroll 8
    for (int k = 0; k < 128; ++k) s += fmaxf(hp[k] + b1[k], 0.0f) * wp[k];
    out[t] = s + b2[o];
}

extern "C" void kernel_launch(void* const* d_in, const int* in_sizes, int n_in,
                              void* d_out, int out_size, void* d_ws, size_t ws_size,
                              hipStream_t stream) {
    const float* x       = (const float*)d_in[0];
    const float* conv1_w = (const float*)d_in[1];
    const float* conv1_b = (const float*)d_in[2];
    const float* conv2_w = (const float*)d_in[3];
    const float* conv2_b = (const float*)d_in[4];
    const float* fc1_w   = (const float*)d_in[5];
    const float* fc1_b   = (const float*)d_in[6];
    const float* fc2_w   = (const float*)d_in[7];
    const float* fc2_b   = (const float*)d_in[8];
    float* out = (float*)d_out;

    char* ws = (char*)d_ws;
    ushort_t* pool1 = (ushort_t*)ws;                         // 512*676*32 bf16 = 22.1 MB
    ws += (size_t)B * POS * 32 * sizeof(ushort_t);
    ushort_t* wr = (ushort_t*)ws;                            // 18,432 bf16
    ws += N_WR * sizeof(ushort_t) + 128;
    ushort_t* wfb = (ushort_t*)ws;                           // 128*9216 bf16 = 2.36 MB
    ws += N_WF * sizeof(ushort_t) + 128;
    ushort_t* pool2b = (ushort_t*)ws;                        // 512*9216 bf16 = 9.44 MB
    ws += (size_t)B * P2SZ * sizeof(ushort_t) + 128;
    float* h3raw = (float*)ws;                               // 512*128 f32 = 256 KB

    {   // conv1 + pool
        int total = B * POS * 32;
        conv1_pool_cl<<<(total + 255) / 256, 256, 0, stream>>>(x, conv1_w, conv1_b, pool1);
    }
    {   // weight prep + accumulator zero
        int total = N_WR + N_WF + N_ZERO;
        prep_k<<<(total + 255) / 256, 256, 0, stream>>>(conv2_w, fc1_w, wr, wfb, h3raw);
    }
    {   // conv2 MFMA
        conv2_mfma<<<B, 768, 0, stream>>>(pool1, wr, conv2_b, pool2b);
    }
    {   // fc1 MFMA split-K
        fc1_mfma<<<256, 256, 0, stream>>>(pool2b, wfb, h3raw);
    }
    {   // fc2 + fused fc1 epilogue
        fc2_fused<<<20, 256, 0, stream>>>(h3raw, fc1_b, fc2_w, fc2_b, out);
    }
}

// Round 4
// 142.348 us; speedup vs baseline: 3.9885x; 1.1768x over previous
//
#include <hip/hip_runtime.h>

// LNSNet forward, R3:
//  - conv1: sliding-window row kernel (thread = [b][py][oc], 26 px per thread)
//  - conv2: bf16 MFMA implicit GEMM, one image/block (unchanged from R2)
//  - fc1:   bf16 MFMA split-K -> plain partials + reduce kernel (no atomics)
//  - fc2:   plain dot on reduced h3

#define B 512
#define POS 676            // 26*26 pooled conv1 spatial
#define ICP 40             // padded ic stride in conv2 LDS
#define P2SZ (64*12*12)    // 9216

typedef unsigned short ushort_t;
typedef ushort_t ushort4v __attribute__((ext_vector_type(4)));
typedef short s16x8 __attribute__((ext_vector_type(8)));
typedef float f32x4 __attribute__((ext_vector_type(4)));

__device__ __forceinline__ ushort_t f2bf(float f) {
    union { float f; unsigned u; } a; a.f = f;
    unsigned r = a.u + 0x7FFFu + ((a.u >> 16) & 1u);   // RNE
    return (ushort_t)(r >> 16);
}
__device__ __forceinline__ float bf2f(ushort_t u) {
    union { unsigned u; float f; } a; a.u = ((unsigned)u) << 16;
    return a.f;
}

// ---------------- conv1 + relu + maxpool2, sliding window ----------------
// thread = [b][py][oc]; walks 26 pooled columns, 4-col register window,
// loads 2 new columns (4x float2) per step. Output channels-last bf16.
__global__ __launch_bounds__(256, 4) void conv1_pool_sl(const float* __restrict__ x,
                                                        const float* __restrict__ w,
                                                        const float* __restrict__ bias,
                                                        ushort_t* __restrict__ out) {
    int t = blockIdx.x * blockDim.x + threadIdx.x;
    if (t >= B * 26 * 32) return;
    int ic = t & 31;
    int r  = t >> 5;          // b*26 + py
    int py = r % 26;
    int b  = r / 26;

    const float* wp = w + ic * 9;
    float w00 = wp[0], w01 = wp[1], w02 = wp[2];
    float w10 = wp[3], w11 = wp[4], w12 = wp[5];
    float w20 = wp[6], w21 = wp[7], w22 = wp[8];
    float bv = bias[ic];

    const float* xr = x + b * (54 * 54) + (2 * py) * 54;
    ushort_t* po = out + ((size_t)b * POS + py * 26) * 32 + ic;

    float2 p[4], q[4];
#pragma unroll
    for (int rr = 0; rr < 4; ++rr) p[rr] = *reinterpret_cast<const float2*>(xr + rr * 54);
#pragma unroll
    for (int rr = 0; rr < 4; ++rr) q[rr] = *reinterpret_cast<const float2*>(xr + rr * 54 + 2);

#pragma unroll
    for (int px = 0; px < 26; ++px) {
        // conv col 2px   : cols p.x p.y q.x ; conv col 2px+1 : cols p.y q.x q.y
        // conv row 2py   : rows 0,1,2       ; conv row 2py+1 : rows 1,2,3
        float s00 = p[0].x * w00 + p[0].y * w01 + q[0].x * w02
                  + p[1].x * w10 + p[1].y * w11 + q[1].x * w12
                  + p[2].x * w20 + p[2].y * w21 + q[2].x * w22;
        float s01 = p[0].y * w00 + q[0].x * w01 + q[0].y * w02
                  + p[1].y * w10 + q[1].x * w11 + q[1].y * w12
                  + p[2].y * w20 + q[2].x * w21 + q[2].y * w22;
        float s10 = p[1].x * w00 + p[1].y * w01 + q[1].x * w02
                  + p[2].x * w10 + p[2].y * w11 + q[2].x * w12
                  + p[3].x * w20 + p[3].y * w21 + q[3].x * w22;
        float s11 = p[1].y * w00 + q[1].x * w01 + q[1].y * w02
                  + p[2].y * w10 + q[2].x * w11 + q[2].y * w12
                  + p[3].y * w20 + q[3].x * w21 + q[3].y * w22;
        float m = fmaxf(fmaxf(s00, s01), fmaxf(s10, s11));
        po[px * 32] = f2bf(fmaxf(m + bv, 0.0f));
        if (px < 25) {
#pragma unroll
            for (int rr = 0; rr < 4; ++rr) {
                p[rr] = q[rr];
                q[rr] = *reinterpret_cast<const float2*>(xr + rr * 54 + 2 * px + 4);
            }
        }
    }
}

// ---------------- prep: conv2 w reshuffle + fc1 w bf16 ----------------
#define N_WR (64 * 9 * 32)          // 18432
#define N_WF (128 * 9216)           // 1179648
__global__ void prep_k(const float* __restrict__ c2w, const float* __restrict__ f1w,
                       ushort_t* __restrict__ wr, ushort_t* __restrict__ wfb) {
    int t = blockIdx.x * blockDim.x + threadIdx.x;
    if (t < N_WR) {
        int ic  = t & 31;
        int tap = (t >> 5) % 9;
        int oc  = t / 288;
        wr[t] = f2bf(c2w[oc * 288 + ic * 9 + tap]);
    } else if (t < N_WR + N_WF) {
        int i = t - N_WR;
        wfb[i] = f2bf(f1w[i]);
    }
}

// ---------------- conv2 MFMA implicit GEMM + relu + pool -> bf16 NCHW ----------------
__global__ __launch_bounds__(768) void conv2_mfma(const ushort_t* __restrict__ p1,
                                                  const ushort_t* __restrict__ wr,
                                                  const float* __restrict__ bias,
                                                  ushort_t* __restrict__ pool2) {
    __shared__ ushort_t lds[POS * ICP];   // 54,080 B
    int b   = blockIdx.x;
    int tid = threadIdx.x;

    const ushort_t* src = p1 + (size_t)b * POS * 32;
    for (int c = tid; c < POS * 8; c += 768) {
        int pos = c >> 3, off = (c & 7) * 4;
        ushort4v v = *reinterpret_cast<const ushort4v*>(src + pos * 32 + off);
        *reinterpret_cast<ushort4v*>(&lds[pos * ICP + off]) = v;
    }
    __syncthreads();

    int lane = tid & 63, wid = tid >> 6;
    int quad = lane >> 4, lr = lane & 15;

    int ebase[3];
#pragma unroll
    for (int t = 0; t < 3; ++t) {
        int m  = t * 16 + lr;
        int yl = m / 24;
        int xx = m - yl * 24;
        ebase[t] = ((wid * 2 + yl) * 26 + xx) * ICP + quad * 8;
    }

    f32x4 acc[3][4];
#pragma unroll
    for (int t = 0; t < 3; ++t)
#pragma unroll
        for (int n = 0; n < 4; ++n) acc[t][n] = (f32x4){0.f, 0.f, 0.f, 0.f};

    const ushort_t* wb = wr + (size_t)lr * 288 + quad * 8;

#pragma unroll
    for (int tap = 0; tap < 9; ++tap) {
        int ky = tap / 3, kx = tap % 3;
        int koff = (ky * 26 + kx) * ICP;
        s16x8 a[3];
#pragma unroll
        for (int t = 0; t < 3; ++t) {
            union { ushort4v s[2]; s16x8 v; } u;
            u.s[0] = *reinterpret_cast<const ushort4v*>(&lds[ebase[t] + koff]);
            u.s[1] = *reinterpret_cast<const ushort4v*>(&lds[ebase[t] + koff + 4]);
            a[t] = u.v;
        }
        s16x8 bf[4];
#pragma unroll
        for (int n = 0; n < 4; ++n)
            bf[n] = *reinterpret_cast<const s16x8*>(wb + n * 4608 + tap * 32);
#pragma unroll
        for (int t = 0; t < 3; ++t)
#pragma unroll
            for (int n = 0; n < 4; ++n)
                acc[t][n] = __builtin_amdgcn_mfma_f32_16x16x32_bf16(a[t], bf[n], acc[t][n], 0, 0, 0);
    }
    __syncthreads();

    ushort_t* scr = lds + wid * 1536;
#pragma unroll
    for (int t = 0; t < 3; ++t)
#pragma unroll
        for (int n = 0; n < 4; ++n) {
            int oc = n * 16 + lr;
            int i0 = t * 8 + quad * 2;
            float v0 = fmaxf(acc[t][n][0], acc[t][n][1]);
            float v1 = fmaxf(acc[t][n][2], acc[t][n][3]);
            union { ushort_t u2[2]; unsigned w; } pk;
            pk.u2[0] = f2bf(v0); pk.u2[1] = f2bf(v1);
            *reinterpret_cast<unsigned*>(&scr[oc * 24 + i0]) = pk.w;
        }
    __syncthreads();

    int oc = lane;
    const ushort_t* row = scr + oc * 24;
    float bv = bias[oc];
    ushort_t outv[12];
#pragma unroll
    for (int px = 0; px < 12; ++px) {
        float r0 = bf2f(row[px]);
        float r1 = bf2f(row[px + 12]);
        outv[px] = f2bf(fmaxf(fmaxf(r0, r1) + bv, 0.0f));
    }
    ushort_t* po = pool2 + ((size_t)(b * 64 + oc) * 144 + wid * 12);
#pragma unroll
    for (int q = 0; q < 3; ++q)
        *reinterpret_cast<ushort4v*>(po + q * 4) =
            (ushort4v){outv[q*4+0], outv[q*4+1], outv[q*4+2], outv[q*4+3]};
}

// ---------------- fc1 bf16 MFMA split-K, plain partials ----------------
// grid = 8 M-tiles x 32 K-splits = 256 blocks, 4 waves.
// wave: 16(M) x 128(N), K-chunk 288; Cpart[ks][512][128] f32.
__global__ __launch_bounds__(256) void fc1_mfma(const ushort_t* __restrict__ A,
                                                 const ushort_t* __restrict__ W,
                                                 float* __restrict__ Cpart) {
    int blk = blockIdx.x;
    int mt = blk & 7;
    int ks = blk >> 3;
    int tid = threadIdx.x;
    int lane = tid & 63, wid = tid >> 6;
    int lr = lane & 15, quad = lane >> 4;

    int m  = mt * 64 + wid * 16 + lr;
    int k0 = ks * 288;
    const ushort_t* arow = A + (size_t)m * 9216 + k0 + quad * 8;
    const ushort_t* wrow = W + (size_t)lr * 9216 + k0 + quad * 8;

    f32x4 acc[8];
#pragma unroll
    for (int n = 0; n < 8; ++n) acc[n] = (f32x4){0.f, 0.f, 0.f, 0.f};

#pragma unroll
    for (int kk = 0; kk < 9; ++kk) {
        s16x8 a = *reinterpret_cast<const s16x8*>(arow + kk * 32);
#pragma unroll
        for (int n = 0; n < 8; ++n) {
            s16x8 bfr = *reinterpret_cast<const s16x8*>(wrow + (size_t)n * 16 * 9216 + kk * 32);
            acc[n] = __builtin_amdgcn_mfma_f32_16x16x32_bf16(a, bfr, acc[n], 0, 0, 0);
        }
    }

    float* cp = Cpart + (size_t)ks * 512 * 128;
    int crow = mt * 64 + wid * 16 + quad * 4;
#pragma unroll
    for (int n = 0; n < 8; ++n)
#pragma unroll
        for (int r = 0; r < 4; ++r)
            cp[(size_t)(crow + r) * 128 + n * 16 + lr] = acc[n][r];
}

// ---------------- fc1 reduce + bias + relu ----------------
__global__ void fc1_reduce(const float* __restrict__ Cpart, const float* __restrict__ b1,
                           float* __restrict__ h3) {
    int t = blockIdx.x * blockDim.x + threadIdx.x;   // 65536
    float s = 0.f;
#pragma unroll
    for (int ks = 0; ks < 32; ++ks) s += Cpart[(size_t)ks * 65536 + t];
    h3[t] = fmaxf(s + b1[t & 127], 0.0f);
}

// ---------------- fc2 ----------------
__global__ void fc2_k(const float* __restrict__ h, const float* __restrict__ w,
                      const float* __restrict__ bias, float* __restrict__ out) {
    int t = blockIdx.x * blockDim.x + threadIdx.x;
    if (t >= B * 10) return;
    int o = t % 10, b = t / 10;
    const float* hp = h + b * 128;
    const float* wp = w + o * 128;
    float s = 0.f;
#pragma unroll 8
    for (int k = 0; k < 128; ++k) s += hp[k] * wp[k];
    out[t] = s + bias[o];
}

extern "C" void kernel_launch(void* const* d_in, const int* in_sizes, int n_in,
                              void* d_out, int out_size, void* d_ws, size_t ws_size,
                              hipStream_t stream) {
    const float* x       = (const float*)d_in[0];
    const float* conv1_w = (const float*)d_in[1];
    const float* conv1_b = (const float*)d_in[2];
    const float* conv2_w = (const float*)d_in[3];
    const float* conv2_b = (const float*)d_in[4];
    const float* fc1_w   = (const float*)d_in[5];
    const float* fc1_b   = (const float*)d_in[6];
    const float* fc2_w   = (const float*)d_in[7];
    const float* fc2_b   = (const float*)d_in[8];
    float* out = (float*)d_out;

    char* ws = (char*)d_ws;
    ushort_t* pool1 = (ushort_t*)ws;                         // 22.1 MB
    ws += (size_t)B * POS * 32 * sizeof(ushort_t);
    ushort_t* wr = (ushort_t*)ws;                            // 36 KB
    ws += N_WR * sizeof(ushort_t) + 128;
    ushort_t* wfb = (ushort_t*)ws;                           // 2.36 MB
    ws += N_WF * sizeof(ushort_t) + 128;
    ushort_t* pool2b = (ushort_t*)ws;                        // 9.44 MB
    ws += (size_t)B * P2SZ * sizeof(ushort_t) + 128;
    float* Cpart = (float*)ws;                               // 32*512*128*4 = 8.39 MB
    ws += (size_t)32 * 512 * 128 * sizeof(float) + 128;
    float* h3 = (float*)ws;                                  // 256 KB

    {   // conv1: 425,984 threads (26 px each)
        int total = B * 26 * 32;
        conv1_pool_sl<<<(total + 255) / 256, 256, 0, stream>>>(x, conv1_w, conv1_b, pool1);
    }
    {   // weight prep
        int total = N_WR + N_WF;
        prep_k<<<(total + 255) / 256, 256, 0, stream>>>(conv2_w, fc1_w, wr, wfb);
    }
    {   // conv2 MFMA
        conv2_mfma<<<B, 768, 0, stream>>>(pool1, wr, conv2_b, pool2b);
    }
    {   // fc1 MFMA split-K partials
        fc1_mfma<<<256, 256, 0, stream>>>(pool2b, wfb, Cpart);
    }
    {   // fc1 reduce + bias + relu
        fc1_reduce<<<256, 256, 0, stream>>>(Cpart, fc1_b, h3);
    }
    {   // fc2
        fc2_k<<<20, 256, 0, stream>>>(h3, fc2_w, fc2_b, out);
    }
}

// Round 5
// 137.612 us; speedup vs baseline: 4.1258x; 1.0344x over previous
//
#include <hip/hip_runtime.h>

// LNSNet forward, R4:
//  - k1: conv1 sliding-row (+fused weight-prep blocks)
//  - k2: conv2 bf16 MFMA, 3 blocks/image (4 waves, 18.7KB LDS, ICP=36 conflict-free)
//  - k3: fc1 bf16 MFMA, 4096 waves (32mt x 16ks x 8nt), plain partials
//  - k4: fc1 reduce + bias + relu + fc2 in one kernel

#define B 512
#define POS 676            // 26*26 pooled conv1 spatial
#define ICP 36             // padded ic stride in conv2 LDS (18-dword stride: conflict-free)
#define P2SZ (64*12*12)    // 9216

typedef unsigned short ushort_t;
typedef ushort_t ushort4v __attribute__((ext_vector_type(4)));
typedef short s16x8 __attribute__((ext_vector_type(8)));
typedef float f32x4 __attribute__((ext_vector_type(4)));

__device__ __forceinline__ ushort_t f2bf(float f) {
    union { float f; unsigned u; } a; a.f = f;
    unsigned r = a.u + 0x7FFFu + ((a.u >> 16) & 1u);   // RNE
    return (ushort_t)(r >> 16);
}
__device__ __forceinline__ float bf2f(ushort_t u) {
    union { unsigned u; float f; } a; a.u = ((unsigned)u) << 16;
    return a.f;
}

#define N_WR (64 * 9 * 32)          // 18432
#define N_WF (128 * 9216)           // 1179648
#define CONV1_BLOCKS 1664           // 512*26*32 / 256
#define PREP_BLOCKS  4680           // (N_WR+N_WF)/256 = 4680

// ---------------- k1: conv1 sliding-row + weight prep ----------------
__global__ __launch_bounds__(256) void conv1_prep(const float* __restrict__ x,
                                                  const float* __restrict__ w,
                                                  const float* __restrict__ bias,
                                                  const float* __restrict__ c2w,
                                                  const float* __restrict__ f1w,
                                                  ushort_t* __restrict__ out,
                                                  ushort_t* __restrict__ wr,
                                                  ushort_t* __restrict__ wfb) {
    int blk = blockIdx.x;
    if (blk >= CONV1_BLOCKS) {
        int t = (blk - CONV1_BLOCKS) * 256 + threadIdx.x;
        if (t < N_WR) {
            int ic  = t & 31;
            int tap = (t >> 5) % 9;
            int oc  = t / 288;
            wr[t] = f2bf(c2w[oc * 288 + ic * 9 + tap]);
        } else if (t < N_WR + N_WF) {
            int i = t - N_WR;
            wfb[i] = f2bf(f1w[i]);
        }
        return;
    }
    int t = blk * 256 + threadIdx.x;
    int ic = t & 31;
    int r  = t >> 5;          // b*26 + py
    int py = r % 26;
    int b  = r / 26;

    const float* wp = w + ic * 9;
    float w00 = wp[0], w01 = wp[1], w02 = wp[2];
    float w10 = wp[3], w11 = wp[4], w12 = wp[5];
    float w20 = wp[6], w21 = wp[7], w22 = wp[8];
    float bv = bias[ic];

    const float* xr = x + b * (54 * 54) + (2 * py) * 54;
    ushort_t* po = out + ((size_t)b * POS + py * 26) * 32 + ic;

    float2 p[4], q[4];
#pragma unroll
    for (int rr = 0; rr < 4; ++rr) p[rr] = *reinterpret_cast<const float2*>(xr + rr * 54);
#pragma unroll
    for (int rr = 0; rr < 4; ++rr) q[rr] = *reinterpret_cast<const float2*>(xr + rr * 54 + 2);

#pragma unroll
    for (int px = 0; px < 26; ++px) {
        float s00 = p[0].x * w00 + p[0].y * w01 + q[0].x * w02
                  + p[1].x * w10 + p[1].y * w11 + q[1].x * w12
                  + p[2].x * w20 + p[2].y * w21 + q[2].x * w22;
        float s01 = p[0].y * w00 + q[0].x * w01 + q[0].y * w02
                  + p[1].y * w10 + q[1].x * w11 + q[1].y * w12
                  + p[2].y * w20 + q[2].x * w21 + q[2].y * w22;
        float s10 = p[1].x * w00 + p[1].y * w01 + q[1].x * w02
                  + p[2].x * w10 + p[2].y * w11 + q[2].x * w12
                  + p[3].x * w20 + p[3].y * w21 + q[3].x * w22;
        float s11 = p[1].y * w00 + q[1].x * w01 + q[1].y * w02
                  + p[2].y * w10 + q[2].x * w11 + q[2].y * w12
                  + p[3].y * w20 + q[3].x * w21 + q[3].y * w22;
        float m = fmaxf(fmaxf(s00, s01), fmaxf(s10, s11));
        po[px * 32] = f2bf(fmaxf(m + bv, 0.0f));
        if (px < 25) {
#pragma unroll
            for (int rr = 0; rr < 4; ++rr) {
                p[rr] = q[rr];
                q[rr] = *reinterpret_cast<const float2*>(xr + rr * 54 + 2 * px + 4);
            }
        }
    }
}

// ---------------- k2: conv2 MFMA, 3 blocks/image ----------------
// block = 256 thr (4 waves), chunk c of image b: pooled rows 4c..4c+3.
// Stages pool1 rows 8c..8c+9 (260 pos) into LDS [pos][36].
// wave w: pooled row 4c+w -> conv rows 2w,2w+1 local (48 m = 3 tiles) x 64 oc.
__global__ __launch_bounds__(256) void conv2_mfma(const ushort_t* __restrict__ p1,
                                                  const ushort_t* __restrict__ wr,
                                                  const float* __restrict__ bias,
                                                  ushort_t* __restrict__ pool2) {
    __shared__ ushort_t lds[260 * ICP];   // 9360 ushort = 18,720 B
    int blk = blockIdx.x;
    int b = blk / 3, c = blk % 3;
    int tid = threadIdx.x;

    const ushort_t* src = p1 + ((size_t)b * POS + 8 * c * 26) * 32;
    for (int t = tid; t < 260 * 8; t += 256) {
        int pos = t >> 3, off = (t & 7) * 4;
        ushort4v v = *reinterpret_cast<const ushort4v*>(src + pos * 32 + off);
        *reinterpret_cast<ushort4v*>(&lds[pos * ICP + off]) = v;
    }
    __syncthreads();

    int lane = tid & 63, wid = tid >> 6;
    int quad = lane >> 4, lr = lane & 15;

    int ebase[3];
#pragma unroll
    for (int t = 0; t < 3; ++t) {
        int m  = t * 16 + lr;
        int yl = m / 24;
        int xx = m - yl * 24;
        ebase[t] = ((2 * wid + yl) * 26 + xx) * ICP + quad * 8;
    }

    f32x4 acc[3][4];
#pragma unroll
    for (int t = 0; t < 3; ++t)
#pragma unroll
        for (int n = 0; n < 4; ++n) acc[t][n] = (f32x4){0.f, 0.f, 0.f, 0.f};

    const ushort_t* wb = wr + (size_t)lr * 288 + quad * 8;

#pragma unroll
    for (int tap = 0; tap < 9; ++tap) {
        int ky = tap / 3, kx = tap % 3;
        int koff = (ky * 26 + kx) * ICP;
        s16x8 a[3];
#pragma unroll
        for (int t = 0; t < 3; ++t) {
            union { ushort4v s[2]; s16x8 v; } u;
            u.s[0] = *reinterpret_cast<const ushort4v*>(&lds[ebase[t] + koff]);
            u.s[1] = *reinterpret_cast<const ushort4v*>(&lds[ebase[t] + koff + 4]);
            a[t] = u.v;
        }
        s16x8 bf[4];
#pragma unroll
        for (int n = 0; n < 4; ++n)
            bf[n] = *reinterpret_cast<const s16x8*>(wb + n * 4608 + tap * 32);
#pragma unroll
        for (int t = 0; t < 3; ++t)
#pragma unroll
            for (int n = 0; n < 4; ++n)
                acc[t][n] = __builtin_amdgcn_mfma_f32_16x16x32_bf16(a[t], bf[n], acc[t][n], 0, 0, 0);
    }
    __syncthreads();   // image LDS dead; reuse as per-wave pooling scratch

    // x-pool in regs -> scratch [wid][oc][i], i = m/2 (0..23)
    ushort_t* scr = lds + wid * 1536;
#pragma unroll
    for (int t = 0; t < 3; ++t)
#pragma unroll
        for (int n = 0; n < 4; ++n) {
            int oc = n * 16 + lr;
            int i0 = t * 8 + quad * 2;
            float v0 = fmaxf(acc[t][n][0], acc[t][n][1]);
            float v1 = fmaxf(acc[t][n][2], acc[t][n][3]);
            union { ushort_t u2[2]; unsigned w; } pk;
            pk.u2[0] = f2bf(v0); pk.u2[1] = f2bf(v1);
            *reinterpret_cast<unsigned*>(&scr[oc * 24 + i0]) = pk.w;
        }
    // y-pool reads only this wave's own scratch: per-wave LDS ordering suffices.
    int oc = lane;
    const ushort_t* row = scr + oc * 24;
    float bv = bias[oc];
    int py = c * 4 + wid;
    ushort_t outv[12];
#pragma unroll
    for (int px = 0; px < 12; ++px) {
        float r0 = bf2f(row[px]);
        float r1 = bf2f(row[px + 12]);
        outv[px] = f2bf(fmaxf(fmaxf(r0, r1) + bv, 0.0f));
    }
    ushort_t* po = pool2 + ((size_t)(b * 64 + oc) * 144 + py * 12);
#pragma unroll
    for (int q = 0; q < 3; ++q)
        *reinterpret_cast<ushort4v*>(po + q * 4) =
            (ushort4v){outv[q*4+0], outv[q*4+1], outv[q*4+2], outv[q*4+3]};
}

// ---------------- k3: fc1 bf16 MFMA, 4096 waves ----------------
// wave = 16m x 16n x 576k (18 ksteps). w = blk*4+wid: nt=w&7, ks=(w>>3)&15, mt=w>>7.
// Waves in a block share mt/ks -> A-frags L1-hot. Cpart[16][512][128] f32.
__global__ __launch_bounds__(256) void fc1_mfma(const ushort_t* __restrict__ A,
                                                 const ushort_t* __restrict__ W,
                                                 float* __restrict__ Cpart) {
    int tid = threadIdx.x;
    int lane = tid & 63, wid = tid >> 6;
    int lr = lane & 15, quad = lane >> 4;
    int w  = blockIdx.x * 4 + wid;
    int nt = w & 7;
    int ks = (w >> 3) & 15;
    int mt = w >> 7;

    int m  = mt * 16 + lr;
    int k0 = ks * 576;
    const ushort_t* arow = A + (size_t)m * 9216 + k0 + quad * 8;
    const ushort_t* wrow = W + (size_t)(nt * 16 + lr) * 9216 + k0 + quad * 8;

    f32x4 acc = (f32x4){0.f, 0.f, 0.f, 0.f};
#pragma unroll
    for (int kk = 0; kk < 18; ++kk) {
        s16x8 a   = *reinterpret_cast<const s16x8*>(arow + kk * 32);
        s16x8 bfr = *reinterpret_cast<const s16x8*>(wrow + kk * 32);
        acc = __builtin_amdgcn_mfma_f32_16x16x32_bf16(a, bfr, acc, 0, 0, 0);
    }

    float* cp = Cpart + (size_t)ks * (512 * 128);
    int crow = mt * 16 + quad * 4;
#pragma unroll
    for (int r = 0; r < 4; ++r)
        cp[(size_t)(crow + r) * 128 + nt * 16 + lr] = acc[r];
}

// ---------------- k4: fc1 reduce + bias + relu + fc2 ----------------
// block = one batch image, 128 threads.
__global__ __launch_bounds__(128) void fc1fc2(const float* __restrict__ Cpart,
                                              const float* __restrict__ b1,
                                              const float* __restrict__ w2,
                                              const float* __restrict__ b2,
                                              float* __restrict__ out) {
    __shared__ float h[128];
    int b = blockIdx.x, k = threadIdx.x;
    float s = 0.f;
#pragma unroll
    for (int ks = 0; ks < 16; ++ks) s += Cpart[(size_t)ks * (512 * 128) + b * 128 + k];
    h[k] = fmaxf(s + b1[k], 0.0f);
    __syncthreads();
    if (k < 10) {
        const float* wp = w2 + k * 128;
        float acc = 0.f;
#pragma unroll 8
        for (int j = 0; j < 128; ++j) acc += h[j] * wp[j];
        out[b * 10 + k] = acc + b2[k];
    }
}

extern "C" void kernel_launch(void* const* d_in, const int* in_sizes, int n_in,
                              void* d_out, int out_size, void* d_ws, size_t ws_size,
                              hipStream_t stream) {
    const float* x       = (const float*)d_in[0];
    const float* conv1_w = (const float*)d_in[1];
    const float* conv1_b = (const float*)d_in[2];
    const float* conv2_w = (const float*)d_in[3];
    const float* conv2_b = (const float*)d_in[4];
    const float* fc1_w   = (const float*)d_in[5];
    const float* fc1_b   = (const float*)d_in[6];
    const float* fc2_w   = (const float*)d_in[7];
    const float* fc2_b   = (const float*)d_in[8];
    float* out = (float*)d_out;

    char* ws = (char*)d_ws;
    ushort_t* pool1 = (ushort_t*)ws;                         // 22.1 MB
    ws += (size_t)B * POS * 32 * sizeof(ushort_t);
    ushort_t* wr = (ushort_t*)ws;                            // 36 KB
    ws += N_WR * sizeof(ushort_t) + 128;
    ushort_t* wfb = (ushort_t*)ws;                           // 2.36 MB
    ws += N_WF * sizeof(ushort_t) + 128;
    ushort_t* pool2b = (ushort_t*)ws;                        // 9.44 MB
    ws += (size_t)B * P2SZ * sizeof(ushort_t) + 128;
    float* Cpart = (float*)ws;                               // 16*512*128*4 = 4.19 MB
    ws += (size_t)16 * 512 * 128 * sizeof(float) + 128;

    {   // k1: conv1 (1664 blocks) + weight prep (4680 blocks)
        conv1_prep<<<CONV1_BLOCKS + PREP_BLOCKS, 256, 0, stream>>>(
            x, conv1_w, conv1_b, conv2_w, fc1_w, pool1, wr, wfb);
    }
    {   // k2: conv2 MFMA, 3 chunks/image
        conv2_mfma<<<B * 3, 256, 0, stream>>>(pool1, wr, conv2_b, pool2b);
    }
    {   // k3: fc1 MFMA, 1024 blocks (4096 waves)
        fc1_mfma<<<1024, 256, 0, stream>>>(pool2b, wfb, Cpart);
    }
    {   // k4: fc1 reduce + fc2
        fc1fc2<<<B, 128, 0, stream>>>(Cpart, fc1_b, fc2_w, fc2_b, out);
    }
}

// Round 6
// 131.331 us; speedup vs baseline: 4.3231x; 1.0478x over previous
//
#include <hip/hip_runtime.h>

// LNSNet forward, R5:
//  - k1: conv1 sliding-row with PACKED fp32 math (v_pk_fma_f32) + fused weight-prep
//  - k2: conv2 bf16 MFMA, 3 blocks/image (unchanged from R4)
//  - k3: fc1 bf16 MFMA, 32x32-tile waves (2A+2B -> 4 MFMA per kstep), 2048 waves
//  - k4: fc1 reduce(32 slabs) + bias + relu + fc2

#define B 512
#define POS 676            // 26*26 pooled conv1 spatial
#define ICP 36             // padded ic stride in conv2 LDS
#define P2SZ (64*12*12)    // 9216

typedef unsigned short ushort_t;
typedef ushort_t ushort4v __attribute__((ext_vector_type(4)));
typedef short s16x8 __attribute__((ext_vector_type(8)));
typedef float f32x4 __attribute__((ext_vector_type(4)));
typedef float f32x2 __attribute__((ext_vector_type(2)));

__device__ __forceinline__ ushort_t f2bf(float f) {
    union { float f; unsigned u; } a; a.f = f;
    unsigned r = a.u + 0x7FFFu + ((a.u >> 16) & 1u);   // RNE
    return (ushort_t)(r >> 16);
}
__device__ __forceinline__ float bf2f(ushort_t u) {
    union { unsigned u; float f; } a; a.u = ((unsigned)u) << 16;
    return a.f;
}

#define N_WR (64 * 9 * 32)          // 18432
#define N_WF (128 * 9216)           // 1179648
#define CONV1_BLOCKS 1664           // 512*26*32 / 256
#define PREP_BLOCKS  4680           // (N_WR+N_WF)/256

// ---------------- k1: conv1 sliding-row (packed fp32) + weight prep ----------------
__global__ __launch_bounds__(256) void conv1_prep(const float* __restrict__ x,
                                                  const float* __restrict__ w,
                                                  const float* __restrict__ bias,
                                                  const float* __restrict__ c2w,
                                                  const float* __restrict__ f1w,
                                                  ushort_t* __restrict__ out,
                                                  ushort_t* __restrict__ wr,
                                                  ushort_t* __restrict__ wfb) {
    int blk = blockIdx.x;
    if (blk >= CONV1_BLOCKS) {
        int t = (blk - CONV1_BLOCKS) * 256 + threadIdx.x;
        if (t < N_WR) {
            int ic  = t & 31;
            int tap = (t >> 5) % 9;
            int oc  = t / 288;
            wr[t] = f2bf(c2w[oc * 288 + ic * 9 + tap]);
        } else if (t < N_WR + N_WF) {
            int i = t - N_WR;
            wfb[i] = f2bf(f1w[i]);
        }
        return;
    }
    int t = blk * 256 + threadIdx.x;
    int ic = t & 31;
    int r  = t >> 5;          // b*26 + py
    int py = r % 26;
    int b  = r / 26;

    const float* wp = w + ic * 9;
    float w00 = wp[0], w01 = wp[1], w02 = wp[2];
    float w10 = wp[3], w11 = wp[4], w12 = wp[5];
    float w20 = wp[6], w21 = wp[7], w22 = wp[8];
    float bv = bias[ic];

    const float* xr = x + b * (54 * 54) + (2 * py) * 54;
    ushort_t* po = out + ((size_t)b * POS + py * 26) * 32 + ic;

    f32x2 p[4], q[4];
#pragma unroll
    for (int rr = 0; rr < 4; ++rr) p[rr] = *reinterpret_cast<const f32x2*>(xr + rr * 54);
#pragma unroll
    for (int rr = 0; rr < 4; ++rr) q[rr] = *reinterpret_cast<const f32x2*>(xr + rr * 54 + 2);

#pragma unroll
    for (int px = 0; px < 26; ++px) {
        // packed eval: s0 = (s00,s01) over conv rows 0..2; s1 = (s10,s11) rows 1..3
        f32x2 mid[4];
#pragma unroll
        for (int rr = 0; rr < 4; ++rr) mid[rr] = (f32x2){p[rr].y, q[rr].x};

        f32x2 s0 = p[0] * (f32x2)w00 + mid[0] * (f32x2)w01 + q[0] * (f32x2)w02
                 + p[1] * (f32x2)w10 + mid[1] * (f32x2)w11 + q[1] * (f32x2)w12
                 + p[2] * (f32x2)w20 + mid[2] * (f32x2)w21 + q[2] * (f32x2)w22;
        f32x2 s1 = p[1] * (f32x2)w00 + mid[1] * (f32x2)w01 + q[1] * (f32x2)w02
                 + p[2] * (f32x2)w10 + mid[2] * (f32x2)w11 + q[2] * (f32x2)w12
                 + p[3] * (f32x2)w20 + mid[3] * (f32x2)w21 + q[3] * (f32x2)w22;

        float m = fmaxf(fmaxf(s0.x, s0.y), fmaxf(s1.x, s1.y));
        po[px * 32] = f2bf(fmaxf(m + bv, 0.0f));
        if (px < 25) {
#pragma unroll
            for (int rr = 0; rr < 4; ++rr) {
                p[rr] = q[rr];
                q[rr] = *reinterpret_cast<const f32x2*>(xr + rr * 54 + 2 * px + 4);
            }
        }
    }
}

// ---------------- k2: conv2 MFMA, 3 blocks/image (unchanged R4) ----------------
__global__ __launch_bounds__(256) void conv2_mfma(const ushort_t* __restrict__ p1,
                                                  const ushort_t* __restrict__ wr,
                                                  const float* __restrict__ bias,
                                                  ushort_t* __restrict__ pool2) {
    __shared__ ushort_t lds[260 * ICP];   // 18,720 B
    int blk = blockIdx.x;
    int b = blk / 3, c = blk % 3;
    int tid = threadIdx.x;

    const ushort_t* src = p1 + ((size_t)b * POS + 8 * c * 26) * 32;
    for (int t = tid; t < 260 * 8; t += 256) {
        int pos = t >> 3, off = (t & 7) * 4;
        ushort4v v = *reinterpret_cast<const ushort4v*>(src + pos * 32 + off);
        *reinterpret_cast<ushort4v*>(&lds[pos * ICP + off]) = v;
    }
    __syncthreads();

    int lane = tid & 63, wid = tid >> 6;
    int quad = lane >> 4, lr = lane & 15;

    int ebase[3];
#pragma unroll
    for (int t = 0; t < 3; ++t) {
        int m  = t * 16 + lr;
        int yl = m / 24;
        int xx = m - yl * 24;
        ebase[t] = ((2 * wid + yl) * 26 + xx) * ICP + quad * 8;
    }

    f32x4 acc[3][4];
#pragma unroll
    for (int t = 0; t < 3; ++t)
#pragma unroll
        for (int n = 0; n < 4; ++n) acc[t][n] = (f32x4){0.f, 0.f, 0.f, 0.f};

    const ushort_t* wb = wr + (size_t)lr * 288 + quad * 8;

#pragma unroll
    for (int tap = 0; tap < 9; ++tap) {
        int ky = tap / 3, kx = tap % 3;
        int koff = (ky * 26 + kx) * ICP;
        s16x8 a[3];
#pragma unroll
        for (int t = 0; t < 3; ++t) {
            union { ushort4v s[2]; s16x8 v; } u;
            u.s[0] = *reinterpret_cast<const ushort4v*>(&lds[ebase[t] + koff]);
            u.s[1] = *reinterpret_cast<const ushort4v*>(&lds[ebase[t] + koff + 4]);
            a[t] = u.v;
        }
        s16x8 bf[4];
#pragma unroll
        for (int n = 0; n < 4; ++n)
            bf[n] = *reinterpret_cast<const s16x8*>(wb + n * 4608 + tap * 32);
#pragma unroll
        for (int t = 0; t < 3; ++t)
#pragma unroll
            for (int n = 0; n < 4; ++n)
                acc[t][n] = __builtin_amdgcn_mfma_f32_16x16x32_bf16(a[t], bf[n], acc[t][n], 0, 0, 0);
    }
    __syncthreads();

    ushort_t* scr = lds + wid * 1536;
#pragma unroll
    for (int t = 0; t < 3; ++t)
#pragma unroll
        for (int n = 0; n < 4; ++n) {
            int oc = n * 16 + lr;
            int i0 = t * 8 + quad * 2;
            float v0 = fmaxf(acc[t][n][0], acc[t][n][1]);
            float v1 = fmaxf(acc[t][n][2], acc[t][n][3]);
            union { ushort_t u2[2]; unsigned w; } pk;
            pk.u2[0] = f2bf(v0); pk.u2[1] = f2bf(v1);
            *reinterpret_cast<unsigned*>(&scr[oc * 24 + i0]) = pk.w;
        }
    int oc = lane;
    const ushort_t* row = scr + oc * 24;
    float bv = bias[oc];
    int py = c * 4 + wid;
    ushort_t outv[12];
#pragma unroll
    for (int px = 0; px < 12; ++px) {
        float r0 = bf2f(row[px]);
        float r1 = bf2f(row[px + 12]);
        outv[px] = f2bf(fmaxf(fmaxf(r0, r1) + bv, 0.0f));
    }
    ushort_t* po = pool2 + ((size_t)(b * 64 + oc) * 144 + py * 12);
#pragma unroll
    for (int q = 0; q < 3; ++q)
        *reinterpret_cast<ushort4v*>(po + q * 4) =
            (ushort4v){outv[q*4+0], outv[q*4+1], outv[q*4+2], outv[q*4+3]};
}

// ---------------- k3: fc1 bf16 MFMA, 32x32-tile waves ----------------
// wave = 32m x 32n x 288k (9 ksteps, 2A+2B loads -> 4 MFMA each).
// w = blk*4+wid: nt=w&3, ks=(w>>2)&31, mt=w>>7. 2048 waves (8/CU).
// Cpart[32][512][128] f32.
__global__ __launch_bounds__(256) void fc1_mfma(const ushort_t* __restrict__ A,
                                                 const ushort_t* __restrict__ W,
                                                 float* __restrict__ Cpart) {
    int tid = threadIdx.x;
    int lane = tid & 63, wid = tid >> 6;
    int lr = lane & 15, quad = lane >> 4;
    int w  = blockIdx.x * 4 + wid;
    int nt = w & 3;
    int ks = (w >> 2) & 31;
    int mt = w >> 7;                 // 0..15

    int m0 = mt * 32;
    int n0 = nt * 32;
    int k0 = ks * 288 + quad * 8;
    const ushort_t* a0 = A + (size_t)(m0 + lr) * 9216 + k0;
    const ushort_t* a1 = a0 + (size_t)16 * 9216;
    const ushort_t* b0 = W + (size_t)(n0 + lr) * 9216 + k0;
    const ushort_t* b1 = b0 + (size_t)16 * 9216;

    f32x4 acc[2][2];
#pragma unroll
    for (int i = 0; i < 2; ++i)
#pragma unroll
        for (int j = 0; j < 2; ++j) acc[i][j] = (f32x4){0.f, 0.f, 0.f, 0.f};

#pragma unroll
    for (int kk = 0; kk < 9; ++kk) {
        s16x8 av0 = *reinterpret_cast<const s16x8*>(a0 + kk * 32);
        s16x8 av1 = *reinterpret_cast<const s16x8*>(a1 + kk * 32);
        s16x8 bv0 = *reinterpret_cast<const s16x8*>(b0 + kk * 32);
        s16x8 bv1 = *reinterpret_cast<const s16x8*>(b1 + kk * 32);
        acc[0][0] = __builtin_amdgcn_mfma_f32_16x16x32_bf16(av0, bv0, acc[0][0], 0, 0, 0);
        acc[0][1] = __builtin_amdgcn_mfma_f32_16x16x32_bf16(av0, bv1, acc[0][1], 0, 0, 0);
        acc[1][0] = __builtin_amdgcn_mfma_f32_16x16x32_bf16(av1, bv0, acc[1][0], 0, 0, 0);
        acc[1][1] = __builtin_amdgcn_mfma_f32_16x16x32_bf16(av1, bv1, acc[1][1], 0, 0, 0);
    }

    float* cp = Cpart + (size_t)ks * (512 * 128);
#pragma unroll
    for (int i = 0; i < 2; ++i) {
        int crow = m0 + i * 16 + quad * 4;
#pragma unroll
        for (int j = 0; j < 2; ++j) {
            int col = n0 + j * 16 + lr;
#pragma unroll
            for (int r = 0; r < 4; ++r)
                cp[(size_t)(crow + r) * 128 + col] = acc[i][j][r];
        }
    }
}

// ---------------- k4: fc1 reduce + bias + relu + fc2 ----------------
__global__ __launch_bounds__(128) void fc1fc2(const float* __restrict__ Cpart,
                                              const float* __restrict__ b1,
                                              const float* __restrict__ w2,
                                              const float* __restrict__ b2,
                                              float* __restrict__ out) {
    __shared__ float h[128];
    int b = blockIdx.x, k = threadIdx.x;
    float s = 0.f;
#pragma unroll
    for (int ks = 0; ks < 32; ++ks) s += Cpart[(size_t)ks * (512 * 128) + b * 128 + k];
    h[k] = fmaxf(s + b1[k], 0.0f);
    __syncthreads();
    if (k < 10) {
        const float* wp = w2 + k * 128;
        float acc = 0.f;
#pragma unroll 8
        for (int j = 0; j < 128; ++j) acc += h[j] * wp[j];
        out[b * 10 + k] = acc + b2[k];
    }
}

extern "C" void kernel_launch(void* const* d_in, const int* in_sizes, int n_in,
                              void* d_out, int out_size, void* d_ws, size_t ws_size,
                              hipStream_t stream) {
    const float* x       = (const float*)d_in[0];
    const float* conv1_w = (const float*)d_in[1];
    const float* conv1_b = (const float*)d_in[2];
    const float* conv2_w = (const float*)d_in[3];
    const float* conv2_b = (const float*)d_in[4];
    const float* fc1_w   = (const float*)d_in[5];
    const float* fc1_b   = (const float*)d_in[6];
    const float* fc2_w   = (const float*)d_in[7];
    const float* fc2_b   = (const float*)d_in[8];
    float* out = (float*)d_out;

    char* ws = (char*)d_ws;
    ushort_t* pool1 = (ushort_t*)ws;                         // 22.1 MB
    ws += (size_t)B * POS * 32 * sizeof(ushort_t);
    ushort_t* wr = (ushort_t*)ws;                            // 36 KB
    ws += N_WR * sizeof(ushort_t) + 128;
    ushort_t* wfb = (ushort_t*)ws;                           // 2.36 MB
    ws += N_WF * sizeof(ushort_t) + 128;
    ushort_t* pool2b = (ushort_t*)ws;                        // 9.44 MB
    ws += (size_t)B * P2SZ * sizeof(ushort_t) + 128;
    float* Cpart = (float*)ws;                               // 32*512*128*4 = 8.39 MB
    ws += (size_t)32 * 512 * 128 * sizeof(float) + 128;

    {   // k1: conv1 (1664 blocks) + weight prep (4680 blocks)
        conv1_prep<<<CONV1_BLOCKS + PREP_BLOCKS, 256, 0, stream>>>(
            x, conv1_w, conv1_b, conv2_w, fc1_w, pool1, wr, wfb);
    }
    {   // k2: conv2 MFMA, 3 chunks/image
        conv2_mfma<<<B * 3, 256, 0, stream>>>(pool1, wr, conv2_b, pool2b);
    }
    {   // k3: fc1 MFMA, 512 blocks (2048 waves)
        fc1_mfma<<<512, 256, 0, stream>>>(pool2b, wfb, Cpart);
    }
    {   // k4: fc1 reduce + fc2
        fc1fc2<<<B, 128, 0, stream>>>(Cpart, fc1_b, fc2_w, fc2_b, out);
    }
}